// Round 1
// baseline (1116.111 us; speedup 1.0000x reference)
//
#include <hip/hip_runtime.h>
#include <stdint.h>
#include <stddef.h>

// ---- problem constants ----
#define BWIN 2048
#define NTOK 49
#define CDIM 384
#define HNUM 12
#define HD   32
#define MTOT (BWIN * NTOK)          // 100352 rows, divisible by 64
#define SCALE 0.17677669529663687f  // 1/sqrt(32)

typedef __attribute__((ext_vector_type(8))) short short8;   // 8 bf16 (4 VGPRs)
typedef __attribute__((ext_vector_type(4))) float floatx4;  // MFMA acc

__device__ __forceinline__ unsigned short f2bf(float f) {
    union { float f; unsigned u; } v; v.f = f;
    unsigned u = v.u;
    u = u + 0x7fffu + ((u >> 16) & 1u);   // round-to-nearest-even
    return (unsigned short)(u >> 16);
}
__device__ __forceinline__ float bf2f(unsigned short b) {
    union { unsigned u; float f; } v; v.u = ((unsigned)b) << 16;
    return v.f;
}

// =====================================================================
// Kernel 1: qkv = x @ qkv_w.T + qkv_b  -> scattered bf16 [3][B][H][N][hd]
// 64x64 block tile, 4 waves in 2x2, each wave 32x32 via 2x2 MFMA 16x16x32.
// =====================================================================
__global__ __launch_bounds__(256) void qkv_kernel(
    const float* __restrict__ x, const float* __restrict__ w,
    const float* __restrict__ bias, unsigned short* __restrict__ outq)
{
    __shared__ __align__(16) unsigned short lA[64][40];  // +8 pad breaks b128 conflicts
    __shared__ __align__(16) unsigned short lB[64][40];

    const int tid = threadIdx.x;
    const int tN = blockIdx.x * 64;   // output-col tile (fast dim: weight reuse in L2)
    const int tM = blockIdx.y * 64;   // token tile

    const int sr = tid >> 2;          // staging row 0..63
    const int sc = (tid & 3) * 8;     // staging col 0,8,16,24

    const float* ax = x + (size_t)(tM + sr) * CDIM + sc;
    const float* bw = w + (size_t)(tN + sr) * CDIM + sc;

    const int lane = tid & 63, wv = tid >> 6;
    const int wm = (wv & 1) << 5, wn = (wv >> 1) << 5;
    const int fr = lane & 15;           // fragment row/col within 16
    const int fk = (lane >> 4) * 8;     // fragment k offset (0 or 8.. pattern over quads)

    floatx4 acc00 = {0,0,0,0}, acc01 = {0,0,0,0}, acc10 = {0,0,0,0}, acc11 = {0,0,0,0};

    for (int k0 = 0; k0 < CDIM; k0 += 32) {
        __syncthreads();
        float4 va0 = *(const float4*)(ax + k0);
        float4 va1 = *(const float4*)(ax + k0 + 4);
        float4 vb0 = *(const float4*)(bw + k0);
        float4 vb1 = *(const float4*)(bw + k0 + 4);
        unsigned short* pa = &lA[sr][sc];
        pa[0] = f2bf(va0.x); pa[1] = f2bf(va0.y); pa[2] = f2bf(va0.z); pa[3] = f2bf(va0.w);
        pa[4] = f2bf(va1.x); pa[5] = f2bf(va1.y); pa[6] = f2bf(va1.z); pa[7] = f2bf(va1.w);
        unsigned short* pb = &lB[sr][sc];
        pb[0] = f2bf(vb0.x); pb[1] = f2bf(vb0.y); pb[2] = f2bf(vb0.z); pb[3] = f2bf(vb0.w);
        pb[4] = f2bf(vb1.x); pb[5] = f2bf(vb1.y); pb[6] = f2bf(vb1.z); pb[7] = f2bf(vb1.w);
        __syncthreads();

        short8 a0 = *(const short8*)&lA[wm      + fr][fk];
        short8 a1 = *(const short8*)&lA[wm + 16 + fr][fk];
        short8 b0 = *(const short8*)&lB[wn      + fr][fk];
        short8 b1 = *(const short8*)&lB[wn + 16 + fr][fk];
        acc00 = __builtin_amdgcn_mfma_f32_16x16x32_bf16(a0, b0, acc00, 0, 0, 0);
        acc01 = __builtin_amdgcn_mfma_f32_16x16x32_bf16(a0, b1, acc01, 0, 0, 0);
        acc10 = __builtin_amdgcn_mfma_f32_16x16x32_bf16(a1, b0, acc10, 0, 0, 0);
        acc11 = __builtin_amdgcn_mfma_f32_16x16x32_bf16(a1, b1, acc11, 0, 0, 0);
    }

    // epilogue: D row=(lane>>4)*4+r, col=lane&15  [verified layout]
    const int r0base = tM + wm + ((lane >> 4) << 2);
    #pragma unroll
    for (int ij = 0; ij < 4; ++ij) {
        const int i = ij >> 1, j = ij & 1;
        floatx4 acc = (ij == 0) ? acc00 : (ij == 1) ? acc01 : (ij == 2) ? acc10 : acc11;
        const int col = tN + wn + j * 16 + fr;
        const float bv = bias[col];
        const int which = col / CDIM;
        const int rem = col - which * CDIM;
        const int h = rem >> 5, d = rem & 31;
        #pragma unroll
        for (int r = 0; r < 4; ++r) {
            const int row = r0base + i * 16 + r;
            const int b = row / NTOK;
            const int n = row - b * NTOK;
            const size_t oidx = ((((size_t)which * BWIN + b) * HNUM + h) * NTOK + n) * HD + d;
            outq[oidx] = f2bf(acc[r] + bv);
        }
    }
}

// =====================================================================
// Kernel 2: per (window, head) attention. qkv bf16 in, bf16 out [token, C].
// =====================================================================
__global__ __launch_bounds__(256) void attn_kernel(
    const unsigned short* __restrict__ qkv, const float* __restrict__ mask,
    const float* __restrict__ rpb, unsigned short* __restrict__ outa)
{
    __shared__ float lq[NTOK][33];
    __shared__ float lk[NTOK][33];
    __shared__ float lv[NTOK][33];
    __shared__ float lat[NTOK][50];

    const int b = blockIdx.x, h = blockIdx.y;
    const int tid = threadIdx.x;
    const size_t base = ((size_t)b * HNUM + h) * (NTOK * HD);
    const size_t WHICH = (size_t)BWIN * HNUM * NTOK * HD;

    for (int i = tid; i < NTOK * HD; i += 256) {
        const int n = i >> 5, d = i & 31;
        lq[n][d] = bf2f(qkv[base + i]);
        lk[n][d] = bf2f(qkv[base + WHICH + i]);
        lv[n][d] = bf2f(qkv[base + 2 * WHICH + i]);
    }
    __syncthreads();

    const float* mrow = mask + (size_t)(b & 63) * (NTOK * NTOK);
    for (int e = tid; e < NTOK * NTOK; e += 256) {
        const int i = e / NTOK, j = e - i * NTOK;
        float s = 0.f;
        #pragma unroll
        for (int d = 0; d < HD; ++d) s += lq[i][d] * lk[j][d];
        const int yi = i / 7, xi = i - yi * 7;
        const int yj = j / 7, xj = j - yj * 7;
        const int rel = (yi - yj + 6) * 13 + (xi - xj + 6);
        lat[i][j] = s * SCALE + rpb[rel * HNUM + h] + mrow[e];
    }
    __syncthreads();

    if (tid < NTOK) {
        float mx = -1e30f;
        for (int j = 0; j < NTOK; ++j) mx = fmaxf(mx, lat[tid][j]);
        float sum = 0.f;
        for (int j = 0; j < NTOK; ++j) {
            const float e = __expf(lat[tid][j] - mx);
            lat[tid][j] = e; sum += e;
        }
        const float inv = 1.f / sum;
        for (int j = 0; j < NTOK; ++j) lat[tid][j] *= inv;
    }
    __syncthreads();

    for (int e = tid; e < NTOK * HD; e += 256) {
        const int i = e >> 5, d = e & 31;
        float s = 0.f;
        #pragma unroll
        for (int m = 0; m < NTOK; ++m) s += lat[i][m] * lv[m][d];
        outa[((size_t)b * NTOK + i) * CDIM + h * HD + d] = f2bf(s);
    }
}

// =====================================================================
// Kernel 3: out = a @ proj_w.T + proj_b   (a bf16 [100352,384], out fp32)
// =====================================================================
__global__ __launch_bounds__(256) void proj_kernel(
    const unsigned short* __restrict__ a, const float* __restrict__ w,
    const float* __restrict__ bias, float* __restrict__ out)
{
    __shared__ __align__(16) unsigned short lA[64][40];
    __shared__ __align__(16) unsigned short lB[64][40];

    const int tid = threadIdx.x;
    const int tN = blockIdx.x * 64;
    const int tM = blockIdx.y * 64;

    const int sr = tid >> 2;
    const int sc = (tid & 3) * 8;

    const unsigned short* aa = a + (size_t)(tM + sr) * CDIM + sc;
    const float* bw = w + (size_t)(tN + sr) * CDIM + sc;

    const int lane = tid & 63, wv = tid >> 6;
    const int wm = (wv & 1) << 5, wn = (wv >> 1) << 5;
    const int fr = lane & 15;
    const int fk = (lane >> 4) * 8;

    floatx4 acc00 = {0,0,0,0}, acc01 = {0,0,0,0}, acc10 = {0,0,0,0}, acc11 = {0,0,0,0};

    for (int k0 = 0; k0 < CDIM; k0 += 32) {
        __syncthreads();
        uint4 va = *(const uint4*)(aa + k0);           // 8 bf16 = 16 B
        float4 vb0 = *(const float4*)(bw + k0);
        float4 vb1 = *(const float4*)(bw + k0 + 4);
        *(uint4*)&lA[sr][sc] = va;
        unsigned short* pb = &lB[sr][sc];
        pb[0] = f2bf(vb0.x); pb[1] = f2bf(vb0.y); pb[2] = f2bf(vb0.z); pb[3] = f2bf(vb0.w);
        pb[4] = f2bf(vb1.x); pb[5] = f2bf(vb1.y); pb[6] = f2bf(vb1.z); pb[7] = f2bf(vb1.w);
        __syncthreads();

        short8 a0 = *(const short8*)&lA[wm      + fr][fk];
        short8 a1 = *(const short8*)&lA[wm + 16 + fr][fk];
        short8 b0 = *(const short8*)&lB[wn      + fr][fk];
        short8 b1 = *(const short8*)&lB[wn + 16 + fr][fk];
        acc00 = __builtin_amdgcn_mfma_f32_16x16x32_bf16(a0, b0, acc00, 0, 0, 0);
        acc01 = __builtin_amdgcn_mfma_f32_16x16x32_bf16(a0, b1, acc01, 0, 0, 0);
        acc10 = __builtin_amdgcn_mfma_f32_16x16x32_bf16(a1, b0, acc10, 0, 0, 0);
        acc11 = __builtin_amdgcn_mfma_f32_16x16x32_bf16(a1, b1, acc11, 0, 0, 0);
    }

    const int r0base = tM + wm + ((lane >> 4) << 2);
    #pragma unroll
    for (int ij = 0; ij < 4; ++ij) {
        const int i = ij >> 1, j = ij & 1;
        floatx4 acc = (ij == 0) ? acc00 : (ij == 1) ? acc01 : (ij == 2) ? acc10 : acc11;
        const int col = tN + wn + j * 16 + fr;
        const float bv = bias[col];
        #pragma unroll
        for (int r = 0; r < 4; ++r) {
            const int row = r0base + i * 16 + r;
            out[(size_t)row * CDIM + col] = acc[r] + bv;
        }
    }
}

// =====================================================================
extern "C" void kernel_launch(void* const* d_in, const int* in_sizes, int n_in,
                              void* d_out, int out_size, void* d_ws, size_t ws_size,
                              hipStream_t stream) {
    const float* x      = (const float*)d_in[0];
    const float* mask   = (const float*)d_in[1];
    const float* qkv_w  = (const float*)d_in[2];
    const float* qkv_b  = (const float*)d_in[3];
    const float* proj_w = (const float*)d_in[4];
    const float* proj_b = (const float*)d_in[5];
    const float* rpb    = (const float*)d_in[6];
    float* out = (float*)d_out;

    unsigned short* ws_qkv  = (unsigned short*)d_ws;                       // 3*B*H*N*hd bf16
    unsigned short* ws_attn = ws_qkv + (size_t)3 * BWIN * HNUM * NTOK * HD; // M*C bf16

    // QKV GEMM: M=100352, N=1152, K=384
    qkv_kernel<<<dim3(1152 / 64, MTOT / 64), 256, 0, stream>>>(x, qkv_w, qkv_b, ws_qkv);
    // Attention: one block per (window, head)
    attn_kernel<<<dim3(BWIN, HNUM), 256, 0, stream>>>(ws_qkv, mask, rpb, ws_attn);
    // Proj GEMM: M=100352, N=384, K=384
    proj_kernel<<<dim3(CDIM / 64, MTOT / 64), 256, 0, stream>>>(ws_attn, proj_w, proj_b, out);
}

// Round 2
// 884.986 us; speedup vs baseline: 1.2612x; 1.2612x over previous
//
#include <hip/hip_runtime.h>
#include <stdint.h>
#include <stddef.h>

// ---- problem constants ----
#define BWIN 2048
#define NTOK 49
#define CDIM 384
#define HNUM 12
#define HD   32
#define MTOT (BWIN * NTOK)          // 100352 rows, divisible by 64
#define SCALE 0.17677669529663687f  // 1/sqrt(32)

typedef __attribute__((ext_vector_type(8))) short short8;   // 8 bf16 (4 VGPRs)
typedef __attribute__((ext_vector_type(4))) float floatx4;  // MFMA acc

__device__ __forceinline__ unsigned short f2bf(float f) {
    union { float f; unsigned u; } v; v.f = f;
    unsigned u = v.u;
    u = u + 0x7fffu + ((u >> 16) & 1u);   // round-to-nearest-even
    return (unsigned short)(u >> 16);
}
__device__ __forceinline__ float bf2f(unsigned short b) {
    union { unsigned u; float f; } v; v.u = ((unsigned)b) << 16;
    return v.f;
}

// =====================================================================
// Kernel 1: qkv = x @ qkv_w.T + qkv_b  -> scattered bf16 [3][B][H][N][hd]
// (unchanged from round 1)
// =====================================================================
__global__ __launch_bounds__(256) void qkv_kernel(
    const float* __restrict__ x, const float* __restrict__ w,
    const float* __restrict__ bias, unsigned short* __restrict__ outq)
{
    __shared__ __align__(16) unsigned short lA[64][40];
    __shared__ __align__(16) unsigned short lB[64][40];

    const int tid = threadIdx.x;
    const int tN = blockIdx.x * 64;
    const int tM = blockIdx.y * 64;

    const int sr = tid >> 2;
    const int sc = (tid & 3) * 8;

    const float* ax = x + (size_t)(tM + sr) * CDIM + sc;
    const float* bw = w + (size_t)(tN + sr) * CDIM + sc;

    const int lane = tid & 63, wv = tid >> 6;
    const int wm = (wv & 1) << 5, wn = (wv >> 1) << 5;
    const int fr = lane & 15;
    const int fk = (lane >> 4) * 8;

    floatx4 acc00 = {0,0,0,0}, acc01 = {0,0,0,0}, acc10 = {0,0,0,0}, acc11 = {0,0,0,0};

    for (int k0 = 0; k0 < CDIM; k0 += 32) {
        __syncthreads();
        float4 va0 = *(const float4*)(ax + k0);
        float4 va1 = *(const float4*)(ax + k0 + 4);
        float4 vb0 = *(const float4*)(bw + k0);
        float4 vb1 = *(const float4*)(bw + k0 + 4);
        unsigned short* pa = &lA[sr][sc];
        pa[0] = f2bf(va0.x); pa[1] = f2bf(va0.y); pa[2] = f2bf(va0.z); pa[3] = f2bf(va0.w);
        pa[4] = f2bf(va1.x); pa[5] = f2bf(va1.y); pa[6] = f2bf(va1.z); pa[7] = f2bf(va1.w);
        unsigned short* pb = &lB[sr][sc];
        pb[0] = f2bf(vb0.x); pb[1] = f2bf(vb0.y); pb[2] = f2bf(vb0.z); pb[3] = f2bf(vb0.w);
        pb[4] = f2bf(vb1.x); pb[5] = f2bf(vb1.y); pb[6] = f2bf(vb1.z); pb[7] = f2bf(vb1.w);
        __syncthreads();

        short8 a0 = *(const short8*)&lA[wm      + fr][fk];
        short8 a1 = *(const short8*)&lA[wm + 16 + fr][fk];
        short8 b0 = *(const short8*)&lB[wn      + fr][fk];
        short8 b1 = *(const short8*)&lB[wn + 16 + fr][fk];
        acc00 = __builtin_amdgcn_mfma_f32_16x16x32_bf16(a0, b0, acc00, 0, 0, 0);
        acc01 = __builtin_amdgcn_mfma_f32_16x16x32_bf16(a0, b1, acc01, 0, 0, 0);
        acc10 = __builtin_amdgcn_mfma_f32_16x16x32_bf16(a1, b0, acc10, 0, 0, 0);
        acc11 = __builtin_amdgcn_mfma_f32_16x16x32_bf16(a1, b1, acc11, 0, 0, 0);
    }

    const int r0base = tM + wm + ((lane >> 4) << 2);
    #pragma unroll
    for (int ij = 0; ij < 4; ++ij) {
        const int i = ij >> 1, j = ij & 1;
        floatx4 acc = (ij == 0) ? acc00 : (ij == 1) ? acc01 : (ij == 2) ? acc10 : acc11;
        const int col = tN + wn + j * 16 + fr;
        const float bv = bias[col];
        const int which = col / CDIM;
        const int rem = col - which * CDIM;
        const int h = rem >> 5, d = rem & 31;
        #pragma unroll
        for (int r = 0; r < 4; ++r) {
            const int row = r0base + i * 16 + r;
            const int b = row / NTOK;
            const int n = row - b * NTOK;
            const size_t oidx = ((((size_t)which * BWIN + b) * HNUM + h) * NTOK + n) * HD + d;
            outq[oidx] = f2bf(acc[r] + bv);
        }
    }
}

// =====================================================================
// Kernel 2 (rewritten): MFMA attention, one (window, head) per block.
// 4 waves; wave w owns output rows [16w, 16w+16).
// QK^T: 4 MFMAs/wave (K=32). Register softmax via shfl over 16-lane
// column groups. P -> LDS (A-layout), PV: 4 MFMAs/wave (K=64).
// =====================================================================
__global__ __launch_bounds__(256) void attn_kernel(
    const unsigned short* __restrict__ qkv, const float* __restrict__ mask,
    const float* __restrict__ rpb, unsigned short* __restrict__ outa)
{
    __shared__ __align__(16) unsigned short lq[64][40];   // Q rows, k=0..31
    __shared__ __align__(16) unsigned short lk[64][40];   // K rows, k=0..31
    __shared__ __align__(16) unsigned short lvt[32][72];  // V^T: [d][j]
    __shared__ __align__(16) unsigned short lp[64][72];   // P (bf16), [i][j]

    const int b = blockIdx.x, h = blockIdx.y;
    const int tid = threadIdx.x;
    const size_t WHICH = (size_t)BWIN * HNUM * NTOK * HD;
    const size_t base = ((size_t)b * HNUM + h) * (NTOK * HD);

    // ---- phase 0: zero pad regions; load Q,K (vectorized 8 bf16) ----
    for (int e = tid; e < 1152; e += 256)                 // zero all of lvt
        ((unsigned*)&lvt[0][0])[e] = 0u;
    if (tid < 240) {                                       // rows 49..63, cols 0..31
        const int r = 49 + (tid >> 4), c = (tid & 15) * 2;
        *(unsigned*)&lq[r][c] = 0u;
        *(unsigned*)&lk[r][c] = 0u;
    }
    if (tid < 196) {                                       // 196 * 8 = 1568 bf16
        const int n = tid >> 2, d = (tid & 3) * 8;
        *(uint4*)&lq[n][d] = *(const uint4*)(qkv + base + tid * 8);
        *(uint4*)&lk[n][d] = *(const uint4*)(qkv + base + WHICH + tid * 8);
    }
    __syncthreads();

    // ---- phase 1: scatter V into V^T ----
    for (int e = tid; e < NTOK * HD; e += 256) {
        const int n = e >> 5, d = e & 31;
        lvt[d][n] = qkv[base + 2 * WHICH + e];
    }
    __syncthreads();

    // ---- phase 2: QK^T + bias + mask + register softmax ----
    const int w = tid >> 6, lane = tid & 63;
    const int cg = lane & 15;          // column within 16-tile
    const int rg = lane >> 4;          // row-group within tile
    const int rbase = 16 * w + rg * 4; // output row base (+r)

    short8 aq = *(const short8*)&lq[16 * w + cg][rg * 8];
    floatx4 s[4];
    #pragma unroll
    for (int j = 0; j < 4; ++j) {
        short8 bk = *(const short8*)&lk[16 * j + cg][rg * 8];
        floatx4 z = {0, 0, 0, 0};
        s[j] = __builtin_amdgcn_mfma_f32_16x16x32_bf16(aq, bk, z, 0, 0, 0);
    }

    const float* mk = mask + (size_t)(b & 63) * (NTOK * NTOK);
    float vals[4][4];
    float m[4] = {-1e30f, -1e30f, -1e30f, -1e30f};
    #pragma unroll
    for (int j = 0; j < 4; ++j) {
        const int col = 16 * j + cg;
        const bool vc = col < NTOK;
        int yj = 0, xj = 0;
        if (vc) { yj = col / 7; xj = col - yj * 7; }
        #pragma unroll
        for (int r = 0; r < 4; ++r) {
            float v = -1e30f;
            if (vc) {
                const int row = rbase + r;
                const int rowc = row < NTOK ? row : NTOK - 1;  // clamp padded rows
                const int yi = rowc / 7, xi = rowc - yi * 7;
                const int rel = (yi - yj + 6) * 13 + (xi - xj + 6);
                v = s[j][r] * SCALE + rpb[rel * HNUM + h] + mk[rowc * NTOK + col];
            }
            vals[j][r] = v;
            m[r] = fmaxf(m[r], v);
        }
    }
    #pragma unroll
    for (int st = 1; st < 16; st <<= 1) {
        #pragma unroll
        for (int r = 0; r < 4; ++r) m[r] = fmaxf(m[r], __shfl_xor(m[r], st));
    }
    float l[4] = {0.f, 0.f, 0.f, 0.f};
    #pragma unroll
    for (int j = 0; j < 4; ++j) {
        const int col = 16 * j + cg;
        #pragma unroll
        for (int r = 0; r < 4; ++r) {
            const float e = (col < NTOK) ? __expf(vals[j][r] - m[r]) : 0.f;
            l[r] += e;
            lp[rbase + r][col] = f2bf(e);
        }
    }
    #pragma unroll
    for (int st = 1; st < 16; st <<= 1) {
        #pragma unroll
        for (int r = 0; r < 4; ++r) l[r] += __shfl_xor(l[r], st);
    }
    float linv[4];
    #pragma unroll
    for (int r = 0; r < 4; ++r) linv[r] = 1.f / l[r];
    __syncthreads();

    // ---- phase 3: O = P @ V^T (K=64, 2 steps), normalize, store ----
    #pragma unroll
    for (int n = 0; n < 2; ++n) {
        floatx4 o = {0, 0, 0, 0};
        #pragma unroll
        for (int kk = 0; kk < 2; ++kk) {
            short8 ap = *(const short8*)&lp[16 * w + cg][kk * 32 + rg * 8];
            short8 bv = *(const short8*)&lvt[16 * n + cg][kk * 32 + rg * 8];
            o = __builtin_amdgcn_mfma_f32_16x16x32_bf16(ap, bv, o, 0, 0, 0);
        }
        #pragma unroll
        for (int r = 0; r < 4; ++r) {
            const int row = rbase + r;
            if (row < NTOK)
                outa[((size_t)b * NTOK + row) * CDIM + h * HD + n * 16 + cg] =
                    f2bf(o[r] * linv[r]);
        }
    }
}

// =====================================================================
// Kernel 3: out = a @ proj_w.T + proj_b   (unchanged from round 1)
// =====================================================================
__global__ __launch_bounds__(256) void proj_kernel(
    const unsigned short* __restrict__ a, const float* __restrict__ w,
    const float* __restrict__ bias, float* __restrict__ out)
{
    __shared__ __align__(16) unsigned short lA[64][40];
    __shared__ __align__(16) unsigned short lB[64][40];

    const int tid = threadIdx.x;
    const int tN = blockIdx.x * 64;
    const int tM = blockIdx.y * 64;

    const int sr = tid >> 2;
    const int sc = (tid & 3) * 8;

    const unsigned short* aa = a + (size_t)(tM + sr) * CDIM + sc;
    const float* bw = w + (size_t)(tN + sr) * CDIM + sc;

    const int lane = tid & 63, wv = tid >> 6;
    const int wm = (wv & 1) << 5, wn = (wv >> 1) << 5;
    const int fr = lane & 15;
    const int fk = (lane >> 4) * 8;

    floatx4 acc00 = {0,0,0,0}, acc01 = {0,0,0,0}, acc10 = {0,0,0,0}, acc11 = {0,0,0,0};

    for (int k0 = 0; k0 < CDIM; k0 += 32) {
        __syncthreads();
        uint4 va = *(const uint4*)(aa + k0);
        float4 vb0 = *(const float4*)(bw + k0);
        float4 vb1 = *(const float4*)(bw + k0 + 4);
        *(uint4*)&lA[sr][sc] = va;
        unsigned short* pb = &lB[sr][sc];
        pb[0] = f2bf(vb0.x); pb[1] = f2bf(vb0.y); pb[2] = f2bf(vb0.z); pb[3] = f2bf(vb0.w);
        pb[4] = f2bf(vb1.x); pb[5] = f2bf(vb1.y); pb[6] = f2bf(vb1.z); pb[7] = f2bf(vb1.w);
        __syncthreads();

        short8 a0 = *(const short8*)&lA[wm      + fr][fk];
        short8 a1 = *(const short8*)&lA[wm + 16 + fr][fk];
        short8 b0 = *(const short8*)&lB[wn      + fr][fk];
        short8 b1 = *(const short8*)&lB[wn + 16 + fr][fk];
        acc00 = __builtin_amdgcn_mfma_f32_16x16x32_bf16(a0, b0, acc00, 0, 0, 0);
        acc01 = __builtin_amdgcn_mfma_f32_16x16x32_bf16(a0, b1, acc01, 0, 0, 0);
        acc10 = __builtin_amdgcn_mfma_f32_16x16x32_bf16(a1, b0, acc10, 0, 0, 0);
        acc11 = __builtin_amdgcn_mfma_f32_16x16x32_bf16(a1, b1, acc11, 0, 0, 0);
    }

    const int r0base = tM + wm + ((lane >> 4) << 2);
    #pragma unroll
    for (int ij = 0; ij < 4; ++ij) {
        const int i = ij >> 1, j = ij & 1;
        floatx4 acc = (ij == 0) ? acc00 : (ij == 1) ? acc01 : (ij == 2) ? acc10 : acc11;
        const int col = tN + wn + j * 16 + fr;
        const float bv = bias[col];
        #pragma unroll
        for (int r = 0; r < 4; ++r) {
            const int row = r0base + i * 16 + r;
            out[(size_t)row * CDIM + col] = acc[r] + bv;
        }
    }
}

// =====================================================================
extern "C" void kernel_launch(void* const* d_in, const int* in_sizes, int n_in,
                              void* d_out, int out_size, void* d_ws, size_t ws_size,
                              hipStream_t stream) {
    const float* x      = (const float*)d_in[0];
    const float* mask   = (const float*)d_in[1];
    const float* qkv_w  = (const float*)d_in[2];
    const float* qkv_b  = (const float*)d_in[3];
    const float* proj_w = (const float*)d_in[4];
    const float* proj_b = (const float*)d_in[5];
    const float* rpb    = (const float*)d_in[6];
    float* out = (float*)d_out;

    unsigned short* ws_qkv  = (unsigned short*)d_ws;
    unsigned short* ws_attn = ws_qkv + (size_t)3 * BWIN * HNUM * NTOK * HD;

    qkv_kernel<<<dim3(1152 / 64, MTOT / 64), 256, 0, stream>>>(x, qkv_w, qkv_b, ws_qkv);
    attn_kernel<<<dim3(BWIN, HNUM), 256, 0, stream>>>(ws_qkv, mask, rpb, ws_attn);
    proj_kernel<<<dim3(CDIM / 64, MTOT / 64), 256, 0, stream>>>(ws_attn, proj_w, proj_b, out);
}

// Round 3
// 703.415 us; speedup vs baseline: 1.5867x; 1.2581x over previous
//
#include <hip/hip_runtime.h>
#include <stdint.h>
#include <stddef.h>

// ---- problem constants ----
#define BWIN 2048
#define NTOK 49
#define CDIM 384
#define HNUM 12
#define HD   32
#define MTOT (BWIN * NTOK)          // 100352 rows = 784 * 128
#define SCALE 0.17677669529663687f  // 1/sqrt(32)

typedef __attribute__((ext_vector_type(8))) short short8;   // 8 bf16 (4 VGPRs)
typedef __attribute__((ext_vector_type(4))) float floatx4;  // MFMA acc

__device__ __forceinline__ unsigned short f2bf(float f) {
    union { float f; unsigned u; } v; v.f = f;
    unsigned u = v.u;
    u = u + 0x7fffu + ((u >> 16) & 1u);   // round-to-nearest-even
    return (unsigned short)(u >> 16);
}
__device__ __forceinline__ float bf2f(unsigned short b) {
    union { unsigned u; float f; } v; v.u = ((unsigned)b) << 16;
    return v.f;
}

// async global->LDS, 16 B per lane; LDS dest = wave-uniform base + lane*16
__device__ __forceinline__ void gload16(const void* g, void* l) {
    __builtin_amdgcn_global_load_lds(
        (const __attribute__((address_space(1))) void*)g,
        (__attribute__((address_space(3))) void*)l, 16, 0, 0);
}

// =====================================================================
// Kernel 0: fp32 -> bf16 pre-convert (x, qkv_w, proj_w), 2048 elems/block
// =====================================================================
#define XBLK  18816   // 100352*384 / 2048
#define WQBLK 216     // 3*384*384 / 2048
#define WPBLK 72      // 384*384   / 2048
__global__ __launch_bounds__(256) void convert_kernel(
    const float* __restrict__ x, const float* __restrict__ wq,
    const float* __restrict__ wp, unsigned short* __restrict__ xbf,
    unsigned short* __restrict__ wqbf, unsigned short* __restrict__ wpbf)
{
    int bid = blockIdx.x;
    const float* src; unsigned short* dst; size_t base;
    if (bid < XBLK)              { src = x;  dst = xbf;  base = (size_t)bid * 2048; }
    else if (bid < XBLK + WQBLK) { src = wq; dst = wqbf; base = (size_t)(bid - XBLK) * 2048; }
    else                         { src = wp; dst = wpbf; base = (size_t)(bid - XBLK - WQBLK) * 2048; }
    const size_t i = base + (size_t)threadIdx.x * 8;
    float4 a = *(const float4*)(src + i);
    float4 b = *(const float4*)(src + i + 4);
    unsigned short o[8] = {f2bf(a.x), f2bf(a.y), f2bf(a.z), f2bf(a.w),
                           f2bf(b.x), f2bf(b.y), f2bf(b.z), f2bf(b.w)};
    *(uint4*)(dst + i) = *(uint4*)o;
}

// =====================================================================
// Kernel 1: qkv = xbf @ wqbf^T + qkv_b -> scattered bf16 [3][B][H][N][hd]
// m97 structure: 128x128 tile, 4 waves 2x2 (64x64 each, 4x4 MFMA),
// BK=32, global_load_lds width=16 into unpadded [128][32] tiles.
// =====================================================================
__global__ __launch_bounds__(256) void qkv_kernel(
    const unsigned short* __restrict__ a, const unsigned short* __restrict__ b,
    const float* __restrict__ bias, unsigned short* __restrict__ outq)
{
    __shared__ __align__(16) unsigned short lA[128 * 32];
    __shared__ __align__(16) unsigned short lB[128 * 32];

    const int tid = threadIdx.x;
    const int lane = tid & 63, w = tid >> 6;
    const int tN = blockIdx.x * 128;
    const int tM = blockIdx.y * 128;

    // staging: wave w covers rows [32w, 32w+32) in two 16-row issues
    const int srow = (w << 5) + (lane >> 2);
    const int scol = (lane & 3) << 3;
    const unsigned short* gA = a + (size_t)(tM + srow) * CDIM + scol;
    const unsigned short* gB = b + (size_t)(tN + srow) * CDIM + scol;
    unsigned short* lAb = lA + (w << 10);
    unsigned short* lBb = lB + (w << 10);

    const int wm = (w & 1) << 6, wn = (w >> 1) << 6;
    const int cg = lane & 15, rg = lane >> 4;

    floatx4 acc[4][4];
    #pragma unroll
    for (int i = 0; i < 4; ++i)
        #pragma unroll
        for (int j = 0; j < 4; ++j) acc[i][j] = (floatx4){0.f, 0.f, 0.f, 0.f};

    for (int k0 = 0; k0 < CDIM; k0 += 32) {
        __syncthreads();
        gload16(gA + k0,              lAb);
        gload16(gA + k0 + 16 * CDIM,  lAb + 512);
        gload16(gB + k0,              lBb);
        gload16(gB + k0 + 16 * CDIM,  lBb + 512);
        __syncthreads();   // drains vmcnt -> staged data visible

        short8 af[4], bfr[4];
        #pragma unroll
        for (int i = 0; i < 4; ++i)
            af[i] = *(const short8*)&lA[(wm + 16 * i + cg) * 32 + rg * 8];
        #pragma unroll
        for (int j = 0; j < 4; ++j)
            bfr[j] = *(const short8*)&lB[(wn + 16 * j + cg) * 32 + rg * 8];
        #pragma unroll
        for (int i = 0; i < 4; ++i)
            #pragma unroll
            for (int j = 0; j < 4; ++j)
                acc[i][j] = __builtin_amdgcn_mfma_f32_16x16x32_bf16(af[i], bfr[j], acc[i][j], 0, 0, 0);
    }

    // epilogue: row=(lane>>4)*4+r within 16-tile, col=lane&15
    const int r0 = tM + wm + (rg << 2);
    #pragma unroll
    for (int j = 0; j < 4; ++j) {
        const int col = tN + wn + 16 * j + cg;
        const float bv = bias[col];
        const int which = col / CDIM;
        const int rem = col - which * CDIM;
        const int h = rem >> 5, d = rem & 31;
        #pragma unroll
        for (int i = 0; i < 4; ++i) {
            #pragma unroll
            for (int r = 0; r < 4; ++r) {
                const int row = r0 + 16 * i + r;
                const int bb = row / NTOK;
                const int n = row - bb * NTOK;
                const size_t oidx = ((((size_t)which * BWIN + bb) * HNUM + h) * NTOK + n) * HD + d;
                outq[oidx] = f2bf(acc[i][j][r] + bv);
            }
        }
    }
}

// =====================================================================
// Kernel 2: MFMA attention (unchanged from round 2)
// =====================================================================
__global__ __launch_bounds__(256) void attn_kernel(
    const unsigned short* __restrict__ qkv, const float* __restrict__ mask,
    const float* __restrict__ rpb, unsigned short* __restrict__ outa)
{
    __shared__ __align__(16) unsigned short lq[64][40];
    __shared__ __align__(16) unsigned short lk[64][40];
    __shared__ __align__(16) unsigned short lvt[32][72];
    __shared__ __align__(16) unsigned short lp[64][72];

    const int b = blockIdx.x, h = blockIdx.y;
    const int tid = threadIdx.x;
    const size_t WHICH = (size_t)BWIN * HNUM * NTOK * HD;
    const size_t base = ((size_t)b * HNUM + h) * (NTOK * HD);

    for (int e = tid; e < 1152; e += 256)
        ((unsigned*)&lvt[0][0])[e] = 0u;
    if (tid < 240) {
        const int r = 49 + (tid >> 4), c = (tid & 15) * 2;
        *(unsigned*)&lq[r][c] = 0u;
        *(unsigned*)&lk[r][c] = 0u;
    }
    if (tid < 196) {
        const int n = tid >> 2, d = (tid & 3) * 8;
        *(uint4*)&lq[n][d] = *(const uint4*)(qkv + base + tid * 8);
        *(uint4*)&lk[n][d] = *(const uint4*)(qkv + base + WHICH + tid * 8);
    }
    __syncthreads();

    for (int e = tid; e < NTOK * HD; e += 256) {
        const int n = e >> 5, d = e & 31;
        lvt[d][n] = qkv[base + 2 * WHICH + e];
    }
    __syncthreads();

    const int w = tid >> 6, lane = tid & 63;
    const int cg = lane & 15;
    const int rg = lane >> 4;
    const int rbase = 16 * w + rg * 4;

    short8 aq = *(const short8*)&lq[16 * w + cg][rg * 8];
    floatx4 s[4];
    #pragma unroll
    for (int j = 0; j < 4; ++j) {
        short8 bk = *(const short8*)&lk[16 * j + cg][rg * 8];
        floatx4 z = {0, 0, 0, 0};
        s[j] = __builtin_amdgcn_mfma_f32_16x16x32_bf16(aq, bk, z, 0, 0, 0);
    }

    const float* mk = mask + (size_t)(b & 63) * (NTOK * NTOK);
    float vals[4][4];
    float m[4] = {-1e30f, -1e30f, -1e30f, -1e30f};
    #pragma unroll
    for (int j = 0; j < 4; ++j) {
        const int col = 16 * j + cg;
        const bool vc = col < NTOK;
        int yj = 0, xj = 0;
        if (vc) { yj = col / 7; xj = col - yj * 7; }
        #pragma unroll
        for (int r = 0; r < 4; ++r) {
            float v = -1e30f;
            if (vc) {
                const int row = rbase + r;
                const int rowc = row < NTOK ? row : NTOK - 1;
                const int yi = rowc / 7, xi = rowc - yi * 7;
                const int rel = (yi - yj + 6) * 13 + (xi - xj + 6);
                v = s[j][r] * SCALE + rpb[rel * HNUM + h] + mk[rowc * NTOK + col];
            }
            vals[j][r] = v;
            m[r] = fmaxf(m[r], v);
        }
    }
    #pragma unroll
    for (int st = 1; st < 16; st <<= 1) {
        #pragma unroll
        for (int r = 0; r < 4; ++r) m[r] = fmaxf(m[r], __shfl_xor(m[r], st));
    }
    float l[4] = {0.f, 0.f, 0.f, 0.f};
    #pragma unroll
    for (int j = 0; j < 4; ++j) {
        const int col = 16 * j + cg;
        #pragma unroll
        for (int r = 0; r < 4; ++r) {
            const float e = (col < NTOK) ? __expf(vals[j][r] - m[r]) : 0.f;
            l[r] += e;
            lp[rbase + r][col] = f2bf(e);
        }
    }
    #pragma unroll
    for (int st = 1; st < 16; st <<= 1) {
        #pragma unroll
        for (int r = 0; r < 4; ++r) l[r] += __shfl_xor(l[r], st);
    }
    float linv[4];
    #pragma unroll
    for (int r = 0; r < 4; ++r) linv[r] = 1.f / l[r];
    __syncthreads();

    #pragma unroll
    for (int n = 0; n < 2; ++n) {
        floatx4 o = {0, 0, 0, 0};
        #pragma unroll
        for (int kk = 0; kk < 2; ++kk) {
            short8 ap = *(const short8*)&lp[16 * w + cg][kk * 32 + rg * 8];
            short8 bv = *(const short8*)&lvt[16 * n + cg][kk * 32 + rg * 8];
            o = __builtin_amdgcn_mfma_f32_16x16x32_bf16(ap, bv, o, 0, 0, 0);
        }
        #pragma unroll
        for (int r = 0; r < 4; ++r) {
            const int row = rbase + r;
            if (row < NTOK)
                outa[((size_t)b * NTOK + row) * CDIM + h * HD + n * 16 + cg] =
                    f2bf(o[r] * linv[r]);
        }
    }
}

// =====================================================================
// Kernel 3: out = a @ wpbf^T + proj_b, same m97 structure, fp32 out
// =====================================================================
__global__ __launch_bounds__(256) void proj_kernel(
    const unsigned short* __restrict__ a, const unsigned short* __restrict__ b,
    const float* __restrict__ bias, float* __restrict__ out)
{
    __shared__ __align__(16) unsigned short lA[128 * 32];
    __shared__ __align__(16) unsigned short lB[128 * 32];

    const int tid = threadIdx.x;
    const int lane = tid & 63, w = tid >> 6;
    const int tN = blockIdx.x * 128;
    const int tM = blockIdx.y * 128;

    const int srow = (w << 5) + (lane >> 2);
    const int scol = (lane & 3) << 3;
    const unsigned short* gA = a + (size_t)(tM + srow) * CDIM + scol;
    const unsigned short* gB = b + (size_t)(tN + srow) * CDIM + scol;
    unsigned short* lAb = lA + (w << 10);
    unsigned short* lBb = lB + (w << 10);

    const int wm = (w & 1) << 6, wn = (w >> 1) << 6;
    const int cg = lane & 15, rg = lane >> 4;

    floatx4 acc[4][4];
    #pragma unroll
    for (int i = 0; i < 4; ++i)
        #pragma unroll
        for (int j = 0; j < 4; ++j) acc[i][j] = (floatx4){0.f, 0.f, 0.f, 0.f};

    for (int k0 = 0; k0 < CDIM; k0 += 32) {
        __syncthreads();
        gload16(gA + k0,             lAb);
        gload16(gA + k0 + 16 * CDIM, lAb + 512);
        gload16(gB + k0,             lBb);
        gload16(gB + k0 + 16 * CDIM, lBb + 512);
        __syncthreads();

        short8 af[4], bfr[4];
        #pragma unroll
        for (int i = 0; i < 4; ++i)
            af[i] = *(const short8*)&lA[(wm + 16 * i + cg) * 32 + rg * 8];
        #pragma unroll
        for (int j = 0; j < 4; ++j)
            bfr[j] = *(const short8*)&lB[(wn + 16 * j + cg) * 32 + rg * 8];
        #pragma unroll
        for (int i = 0; i < 4; ++i)
            #pragma unroll
            for (int j = 0; j < 4; ++j)
                acc[i][j] = __builtin_amdgcn_mfma_f32_16x16x32_bf16(af[i], bfr[j], acc[i][j], 0, 0, 0);
    }

    const int r0 = tM + wm + (rg << 2);
    #pragma unroll
    for (int j = 0; j < 4; ++j) {
        const int col = tN + wn + 16 * j + cg;
        const float bv = bias[col];
        #pragma unroll
        for (int i = 0; i < 4; ++i) {
            #pragma unroll
            for (int r = 0; r < 4; ++r) {
                const int row = r0 + 16 * i + r;
                out[(size_t)row * CDIM + col] = acc[i][j][r] + bv;
            }
        }
    }
}

// =====================================================================
extern "C" void kernel_launch(void* const* d_in, const int* in_sizes, int n_in,
                              void* d_out, int out_size, void* d_ws, size_t ws_size,
                              hipStream_t stream) {
    const float* x      = (const float*)d_in[0];
    const float* mask   = (const float*)d_in[1];
    const float* qkv_w  = (const float*)d_in[2];
    const float* qkv_b  = (const float*)d_in[3];
    const float* proj_w = (const float*)d_in[4];
    const float* proj_b = (const float*)d_in[5];
    const float* rpb    = (const float*)d_in[6];
    float* out = (float*)d_out;

    unsigned short* ws_qkv  = (unsigned short*)d_ws;                        // 3*B*H*N*hd
    unsigned short* xbf     = ws_qkv + (size_t)3 * BWIN * HNUM * NTOK * HD; // M*C (aliased)
    unsigned short* ws_attn = xbf;   // x_bf16 dead once qkv_kernel completes
    unsigned short* wqbf    = xbf + (size_t)MTOT * CDIM;                    // 3*C*C
    unsigned short* wpbf    = wqbf + (size_t)3 * CDIM * CDIM;               // C*C

    convert_kernel<<<XBLK + WQBLK + WPBLK, 256, 0, stream>>>(x, qkv_w, proj_w, xbf, wqbf, wpbf);
    qkv_kernel<<<dim3(1152 / 128, MTOT / 128), 256, 0, stream>>>(xbf, wqbf, qkv_b, ws_qkv);
    attn_kernel<<<dim3(BWIN, HNUM), 256, 0, stream>>>(ws_qkv, mask, rpb, ws_attn);
    proj_kernel<<<dim3(CDIM / 128, MTOT / 128), 256, 0, stream>>>(ws_attn, wpbf, proj_b, out);
}